// Round 4
// baseline (91.148 us; speedup 1.0000x reference)
//
#include <hip/hip_runtime.h>
#include <math.h>

// L = diag((W+W^T).sum(1)) - (W+W^T), cotangent weights per face.
// Single-kernel design: each block owns ROWS=4 output rows. It scans all
// faces (cheap range-reject), bins matching contributions into tiny LDS
// lists, merges them into 32 accumulator registers per thread, and streams
// the rows out as coalesced float4 stores. No workspace, no memset, 1 node.

#define ROWS 4
#define CAP  96   // entries per row; degree ~ 2*Poisson(6)+1 => P(>95) ~ 1e-30

typedef float v4f __attribute__((ext_vector_type(4)));

__device__ __forceinline__ void cot_weights(const float* __restrict__ V,
                                            int i0, int i1, int i2,
                                            float& c0, float& c1, float& c2) {
    const float ax = V[i0 * 3 + 0], ay = V[i0 * 3 + 1], az = V[i0 * 3 + 2];
    const float bx = V[i1 * 3 + 0], by = V[i1 * 3 + 1], bz = V[i1 * 3 + 2];
    const float cx = V[i2 * 3 + 0], cy = V[i2 * 3 + 1], cz = V[i2 * 3 + 2];

    float dx, dy, dz, d2;
    dx = bx - cx; dy = by - cy; dz = bz - cz;
    d2 = dx * dx + dy * dy + dz * dz;
    const float l1 = (d2 > 0.0f) ? sqrtf(d2) : 0.0f;
    dx = cx - ax; dy = cy - ay; dz = cz - az;
    d2 = dx * dx + dy * dy + dz * dz;
    const float l2 = (d2 > 0.0f) ? sqrtf(d2) : 0.0f;
    dx = ax - bx; dy = ay - by; dz = az - bz;
    d2 = dx * dx + dy * dy + dz * dz;
    const float l3 = (d2 > 0.0f) ? sqrtf(d2) : 0.0f;

    const float sp = (l1 + l2 + l3) * 0.5f;
    const float s  = sp * (sp - l1) * (sp - l2) * (sp - l3);
    const float A  = (s > 0.0f) ? 2.0f * sqrtf(s) : 1.0f;

    c0 = ((l2 * l2 + l3 * l3 - l1 * l1) / A) * 0.25f; // (r=i1, c=i2)
    c1 = ((l1 * l1 + l3 * l3 - l2 * l2) / A) * 0.25f; // (r=i2, c=i0)
    c2 = ((l1 * l1 + l2 * l2 - l3 * l3) / A) * 0.25f; // (r=i0, c=i1)
}

// N must be 8192 (32 accumulator floats/thread = 8 float4-segments * 256 thr).
__global__ __launch_bounds__(256) void laplacian_rows_kernel(
        const float* __restrict__ V, const int* __restrict__ Fw,
        float* __restrict__ L, int nF) {
    __shared__ int   scol[ROWS][CAP];
    __shared__ float sval[ROWS][CAP];
    __shared__ float sdiag[ROWS];
    __shared__ int   scnt[ROWS];

    const int tid = threadIdx.x;
    const int r0  = blockIdx.x * ROWS;

    if (tid < ROWS) { scnt[tid] = 0; sdiag[tid] = 0.0f; }
    __syncthreads();

    // int64 vs int32 layout detection (little-endian high words all zero)
    const bool is64 = (Fw[1] == 0) && (Fw[3] == 0) && (Fw[5] == 0) &&
                      (Fw[7] == 0) && (Fw[9] == 0) && (Fw[11] == 0);

    // ---- scan all faces; bin contributions touching rows [r0, r0+ROWS) ----
    for (int f = tid; f < nF; f += 256) {
        int i0, i1, i2;
        if (is64) { i0 = Fw[f * 6]; i1 = Fw[f * 6 + 2]; i2 = Fw[f * 6 + 4]; }
        else      { i0 = Fw[f * 3]; i1 = Fw[f * 3 + 1]; i2 = Fw[f * 3 + 2]; }

        const unsigned u0 = (unsigned)(i0 - r0);
        const unsigned u1 = (unsigned)(i1 - r0);
        const unsigned u2 = (unsigned)(i2 - r0);
        if (u0 >= ROWS && u1 >= ROWS && u2 >= ROWS) continue;  // ~99.85% reject

        float c0, c1, c2;
        cot_weights(V, i0, i1, i2, c0, c1, c2);

        const int rr_[3] = {i1, i2, i0};
        const int cc_[3] = {i2, i0, i1};
        const float vv_[3] = {c0, c1, c2};
#pragma unroll
        for (int t = 0; t < 3; ++t) {
            const int r = rr_[t], c = cc_[t];
            const float v = vv_[t];
            const unsigned lr = (unsigned)(r - r0);
            if (lr < ROWS) {
                const int s = atomicAdd(&scnt[lr], 1);
                if (s < CAP - 1) { scol[lr][s] = c; sval[lr][s] = -v; }
                atomicAdd(&sdiag[lr], v);
            }
            const unsigned lc = (unsigned)(c - r0);
            if (lc < ROWS) {
                const int s = atomicAdd(&scnt[lc], 1);
                if (s < CAP - 1) { scol[lc][s] = r; sval[lc][s] = -v; }
                atomicAdd(&sdiag[lc], v);
            }
        }
    }
    __syncthreads();

    // append the diagonal as a regular entry (column = row)
    if (tid < ROWS) {
        int s = scnt[tid];
        if (s > CAP - 1) s = CAP - 1;
        scol[tid][s] = r0 + tid;
        sval[tid][s] = sdiag[tid];
        scnt[tid] = s + 1;
    }
    __syncthreads();

    // ---- per row: merge entries into registers, stream the row out ----
#define CASE_(i) case i: o[i] += v; break;
    for (int rloc = 0; rloc < ROWS; ++rloc) {
        const int row = r0 + rloc;
        float o[32];
#pragma unroll
        for (int i = 0; i < 32; ++i) o[i] = 0.0f;

        const int k = scnt[rloc];
        for (int e = 0; e < k; ++e) {
            const int   c = scol[rloc][e];   // LDS broadcast (uniform addr)
            const float v = sval[rloc][e];
            if (((c >> 2) & 255) == tid) {   // exactly one owner thread / block
                const int idx = ((c >> 10) << 2) | (c & 3);  // 0..31, static cases
                switch (idx) {
                    CASE_(0)  CASE_(1)  CASE_(2)  CASE_(3)
                    CASE_(4)  CASE_(5)  CASE_(6)  CASE_(7)
                    CASE_(8)  CASE_(9)  CASE_(10) CASE_(11)
                    CASE_(12) CASE_(13) CASE_(14) CASE_(15)
                    CASE_(16) CASE_(17) CASE_(18) CASE_(19)
                    CASE_(20) CASE_(21) CASE_(22) CASE_(23)
                    CASE_(24) CASE_(25) CASE_(26) CASE_(27)
                    CASE_(28) CASE_(29) CASE_(30) CASE_(31)
                }
            }
        }

        float* rowp = L + (size_t)row * 8192;
#pragma unroll
        for (int i = 0; i < 8; ++i) {
            v4f t;
            t[0] = o[4 * i + 0]; t[1] = o[4 * i + 1];
            t[2] = o[4 * i + 2]; t[3] = o[4 * i + 3];
            *(v4f*)(rowp + 4 * (tid + (i << 8))) = t;
        }
    }
#undef CASE_
}

// ---- generic fallback (N != 8192): zero output + global-atomic scatter ----
__global__ void face_scatter_kernel(const float* __restrict__ V, const int* __restrict__ Fw,
                                    float* __restrict__ L, int nF, int N) {
    int f = blockIdx.x * blockDim.x + threadIdx.x;
    if (f >= nF) return;
    const bool is64 = (Fw[1] == 0) && (Fw[3] == 0) && (Fw[5] == 0) &&
                      (Fw[7] == 0) && (Fw[9] == 0) && (Fw[11] == 0);
    int i0, i1, i2;
    if (is64) { i0 = Fw[f * 6]; i1 = Fw[f * 6 + 2]; i2 = Fw[f * 6 + 4]; }
    else      { i0 = Fw[f * 3]; i1 = Fw[f * 3 + 1]; i2 = Fw[f * 3 + 2]; }
    float c0, c1, c2;
    cot_weights(V, i0, i1, i2, c0, c1, c2);
    const int rr_[3] = {i1, i2, i0};
    const int cc_[3] = {i2, i0, i1};
    const float vv_[3] = {c0, c1, c2};
    const size_t n = (size_t)N;
#pragma unroll
    for (int t = 0; t < 3; ++t) {
        const int r = rr_[t], c = cc_[t];
        const float v = vv_[t];
        atomicAdd(&L[(size_t)r * n + c], -v);
        atomicAdd(&L[(size_t)c * n + r], -v);
        atomicAdd(&L[(size_t)r * n + r],  v);
        atomicAdd(&L[(size_t)c * n + c],  v);
    }
}

extern "C" void kernel_launch(void* const* d_in, const int* in_sizes, int n_in,
                              void* d_out, int out_size, void* d_ws, size_t ws_size,
                              hipStream_t stream) {
    const float* V = (const float*)d_in[0];
    const int* Fw  = (const int*)d_in[1];
    float* L       = (float*)d_out;

    const int N  = in_sizes[0] / 3;   // 8192 vertices
    const int nF = in_sizes[1] / 3;   // 16384 faces

    if (N == 8192) {
        // one node, no workspace, no memset
        laplacian_rows_kernel<<<N / ROWS, 256, 0, stream>>>(V, Fw, L, nF);
    } else {
        hipMemsetAsync(d_out, 0, (size_t)out_size * sizeof(float), stream);
        const int block = 256;
        face_scatter_kernel<<<(nF + block - 1) / block, block, 0, stream>>>(V, Fw, L, nF, N);
    }
}